// Round 12
// baseline (323.728 us; speedup 1.0000x reference)
//
#include <hip/hip_runtime.h>
#include <hip/hip_bf16.h>

// GroupedQueryAttention: B=2,S=2048,D=2048,H=16,G=4,HD=128, causal, rmsnorm+rope.
// Inputs fp32; OUTPUT fp32. Internal compute bf16 MFMA / fp32 accumulate.
// R21 = R20 + (a) q-RMSNorm/RoPE fused into attn Q-prologue (lane-local RoPE
// pairing kk<->kk+2; quad-group shfl reduce; kt loop untouched; mid_fused
// drops its q range -> 6656 blocks, saves 33.6MB round-trip), (b) qkv XCD
// region swizzle (4y x 8x per XCD: A 128->32MB, B 12->48MB), (c) out XCD
// m-band swizzle (A 128->16MB, B 8->64MB). bid%8=XCD confirmed by R18 FETCH/8.
// ws (58.7 MB): qb | kb | vb | vtb | ctx(=xb alias) | wqb(=wob) | wkb | wvb

typedef __bf16 bf16_t;
using bf16x4 = __attribute__((ext_vector_type(4))) __bf16;
using bf16x8 = __attribute__((ext_vector_type(8))) __bf16;
using f32x4  = __attribute__((ext_vector_type(4))) float;

#define LDSCP16(gp, lp)                                                       \
  __builtin_amdgcn_global_load_lds(                                           \
      (__attribute__((address_space(1))) void*)(gp),                          \
      (__attribute__((address_space(3))) void*)(lp), 16, 0, 0)

// ---------- merged fp32 -> bf16 casts: x | Wq | Wk | Wv ----------
__global__ __launch_bounds__(256) void cast_all(
    const float* __restrict__ x, const float* __restrict__ wq,
    const float* __restrict__ wk, const float* __restrict__ wv,
    bf16_t* __restrict__ xb, bf16_t* __restrict__ wqb,
    bf16_t* __restrict__ wkb, bf16_t* __restrict__ wvb) {
  int blk = blockIdx.x;
  const float* s;
  bf16_t* d;
  size_t base;
  if (blk < 4096)      { s = x;  d = xb;  base = blk; }
  else if (blk < 6144) { s = wq; d = wqb; base = blk - 4096; }
  else if (blk < 6656) { s = wk; d = wkb; base = blk - 6144; }
  else                 { s = wv; d = wvb; base = blk - 6656; }
  size_t i = base * 256 + threadIdx.x;
  const float* g = s + i * 8;
  f32x4 u0 = *(const f32x4*)g;
  f32x4 u1 = *(const f32x4*)(g + 4);
  bf16x8 v;
  v[0] = (bf16_t)u0[0]; v[1] = (bf16_t)u0[1]; v[2] = (bf16_t)u0[2]; v[3] = (bf16_t)u0[3];
  v[4] = (bf16_t)u1[0]; v[5] = (bf16_t)u1[1]; v[6] = (bf16_t)u1[2]; v[7] = (bf16_t)u1[3];
  *(bf16x8*)(d + i * 8) = v;
}

// ---------- 256x192-tile counted-vmcnt GEMM mainloop (qkv): C = A*B^T -------
// 512 thr = 8 waves (2M x 4N), wave tile 128x48, BK=64, dbuf LDS 112KB.
// B = contiguous [3072,2048] (Wq|Wk|Wv). 7 load-units/K-tile (A 4, B 3).
// Read regions: P0 = A{0-63,128-191} + B{0-31,48-79,96-127,144-175};
// P1 = B{32-47,80-95,128-143,176-191}; P2 = A{64-127,192-255}.
// Group g stages tile t+2 into its OWN buffer one phase after each region's
// reads complete (P1: A-half0+B0, P2: B1, P3: A-half1). Swap waits vmcnt(7)
// (this group's 7 loads in flight; tile t+1 landed). Drain only at tail.
__device__ __forceinline__ void gemm256x192_loop(const bf16_t* __restrict__ A,
                                                 const bf16_t* __restrict__ B,
                                                 int K, int m0, int n0,
                                                 bf16_t (*As)[256 * 64],
                                                 bf16_t (*Bs)[192 * 64],
                                                 f32x4 (&acc)[8][3]) {
  const int tid = threadIdx.x;
  const int lane = tid & 63, wid = tid >> 6;
  const int quad = lane >> 4, l16 = lane & 15;
  const int am = (wid >> 2) * 128;   // wave's A-row base (2 M-halves)
  const int bn = (wid & 3) * 48;     // wave's B-row base (4 N-quarters of 48)
  const int NT = K >> 6;

  // A-region (2 units): rows (r&63) + (r>>6)*128 + off (off=0 or 64)
  auto stageA = [&](int t, int wb, int off) {
#pragma unroll
    for (int i2 = 0; i2 < 2; ++i2) {
      int i = i2 * 512 + tid;
      int r = i >> 3, ch = i & 7;
      int row = (r & 63) + ((r >> 6) << 7) + off;
      int sc = ch ^ (row & 7);
      LDSCP16(A + (size_t)(m0 + row) * K + (size_t)t * 64 + sc * 8,
              (bf16_t*)As[wb] + (size_t)row * 64 + ch * 8);
    }
  };
  // B0 (2 units): rows (r&31) + (r>>5)*48 -> {0-31,48-79,96-127,144-175}
  auto stageB0 = [&](int t, int wb) {
#pragma unroll
    for (int i2 = 0; i2 < 2; ++i2) {
      int i = i2 * 512 + tid;
      int r = i >> 3, ch = i & 7;
      int row = (r & 31) + (r >> 5) * 48;
      int sc = ch ^ (row & 7);
      LDSCP16(B + (size_t)(n0 + row) * K + (size_t)t * 64 + sc * 8,
              (bf16_t*)Bs[wb] + (size_t)row * 64 + ch * 8);
    }
  };
  // B1 (1 unit): rows 32 + (r&15) + (r>>4)*48 -> {32-47,80-95,128-143,176-191}
  auto stageB1 = [&](int t, int wb) {
    int r = tid >> 3, ch = tid & 7;
    int row = 32 + (r & 15) + (r >> 4) * 48;
    int sc = ch ^ (row & 7);
    LDSCP16(B + (size_t)(n0 + row) * K + (size_t)t * 64 + sc * 8,
            (bf16_t*)Bs[wb] + (size_t)row * 64 + ch * 8);
  };

  // prologue: tile0 -> buf0, tile1 -> buf1 (7 loads each); wait tile0.
  stageA(0, 0, 0); stageB0(0, 0); stageB1(0, 0); stageA(0, 0, 64);
  stageA(1, 1, 0); stageB0(1, 1); stageB1(1, 1); stageA(1, 1, 64);
  asm volatile("s_waitcnt vmcnt(7)" ::: "memory");
  __builtin_amdgcn_s_barrier();

  bf16x8 af[4][2], bfr[3][2];

  auto group = [&](int g, const int rb) {
    const char* Ab = (const char*)As[rb];
    const char* Bb = (const char*)Bs[rb];
    const bool pf = (g + 2 < NT);

    // ---- P0: ds_read af[mf0-3] (8) + bfr[nf0-1] (4); no staging ----
#pragma unroll
    for (int mf = 0; mf < 4; ++mf)
#pragma unroll
      for (int kk = 0; kk < 2; ++kk) {
        int ra = am + mf * 16 + l16;
        af[mf][kk] = *(const bf16x8*)(Ab + ra * 128 +
                                      (((kk * 4 + quad) ^ (ra & 7)) << 4));
      }
#pragma unroll
    for (int nf = 0; nf < 2; ++nf)
#pragma unroll
      for (int kk = 0; kk < 2; ++kk) {
        int rn = bn + nf * 16 + l16;
        bfr[nf][kk] = *(const bf16x8*)(Bb + rn * 128 +
                                       (((kk * 4 + quad) ^ (rn & 7)) << 4));
      }
    __builtin_amdgcn_s_barrier();
    __builtin_amdgcn_sched_barrier(0);
    __builtin_amdgcn_s_setprio(1);
#pragma unroll
    for (int kk = 0; kk < 2; ++kk)
#pragma unroll
      for (int mf = 0; mf < 4; ++mf)
#pragma unroll
        for (int nf = 0; nf < 2; ++nf)
          acc[mf][nf] = __builtin_amdgcn_mfma_f32_16x16x32_bf16(
              af[mf][kk], bfr[nf][kk], acc[mf][nf], 0, 0, 0);
    __builtin_amdgcn_s_setprio(0);
    __builtin_amdgcn_sched_barrier(0);
    __builtin_amdgcn_s_barrier();
    __builtin_amdgcn_sched_barrier(0);

    // ---- P1: ds_read bfr[nf2] (2); stage A-half0 + B0 of t+2 (4) ----
#pragma unroll
    for (int kk = 0; kk < 2; ++kk) {
      int rn = bn + 32 + l16;
      bfr[2][kk] = *(const bf16x8*)(Bb + rn * 128 +
                                    (((kk * 4 + quad) ^ (rn & 7)) << 4));
    }
    if (pf) { stageA(g + 2, rb, 0); stageB0(g + 2, rb); }
    __builtin_amdgcn_s_barrier();
    __builtin_amdgcn_sched_barrier(0);
    __builtin_amdgcn_s_setprio(1);
#pragma unroll
    for (int kk = 0; kk < 2; ++kk)
#pragma unroll
      for (int mf = 0; mf < 4; ++mf)
        acc[mf][2] = __builtin_amdgcn_mfma_f32_16x16x32_bf16(
            af[mf][kk], bfr[2][kk], acc[mf][2], 0, 0, 0);
    __builtin_amdgcn_s_setprio(0);
    __builtin_amdgcn_sched_barrier(0);
    __builtin_amdgcn_s_barrier();
    __builtin_amdgcn_sched_barrier(0);

    // ---- P2: ds_read af[mf4-7] (8, regs reused); stage B1(t+2) (1) ----
#pragma unroll
    for (int mf = 0; mf < 4; ++mf)
#pragma unroll
      for (int kk = 0; kk < 2; ++kk) {
        int ra = am + 64 + mf * 16 + l16;
        af[mf][kk] = *(const bf16x8*)(Ab + ra * 128 +
                                      (((kk * 4 + quad) ^ (ra & 7)) << 4));
      }
    if (pf) stageB1(g + 2, rb);
    __builtin_amdgcn_s_barrier();
    __builtin_amdgcn_sched_barrier(0);
    __builtin_amdgcn_s_setprio(1);
#pragma unroll
    for (int kk = 0; kk < 2; ++kk)
#pragma unroll
      for (int mf = 0; mf < 4; ++mf)
        acc[mf + 4][2] = __builtin_amdgcn_mfma_f32_16x16x32_bf16(
            af[mf][kk], bfr[2][kk], acc[mf + 4][2], 0, 0, 0);
    __builtin_amdgcn_s_setprio(0);
    __builtin_amdgcn_sched_barrier(0);
    __builtin_amdgcn_s_barrier();
    __builtin_amdgcn_sched_barrier(0);

    // ---- P3: stage A-half1(t+2) (2); MFMA mf4-7 x nf0-1 (reg-only); swap ----
    if (pf) stageA(g + 2, rb, 64);
    __builtin_amdgcn_sched_barrier(0);
    __builtin_amdgcn_s_setprio(1);
#pragma unroll
    for (int kk = 0; kk < 2; ++kk)
#pragma unroll
      for (int mf = 0; mf < 4; ++mf)
#pragma unroll
        for (int nf = 0; nf < 2; ++nf)
          acc[mf + 4][nf] = __builtin_amdgcn_mfma_f32_16x16x32_bf16(
              af[mf][kk], bfr[nf][kk], acc[mf + 4][nf], 0, 0, 0);
    __builtin_amdgcn_s_setprio(0);
    __builtin_amdgcn_sched_barrier(0);
    if (g + 2 < NT)      asm volatile("s_waitcnt vmcnt(7)" ::: "memory");
    else if (g + 1 < NT) asm volatile("s_waitcnt vmcnt(0)" ::: "memory");
    __builtin_amdgcn_s_barrier();
  };

  for (int g2 = 0; g2 < NT; g2 += 2) {
    group(g2, 0);
    group(g2 + 1, 1);
  }
}

// ---------- fused QKV projection; writes head-major [B,Hn,S,HD] bf16 ----------
// B = contiguous Wq|Wk|Wv [3072,2048]; 1D grid 256 with XCD region swizzle:
// XCD i owns m-rows [4(i&3),+4) x n-cols [8(i>>2),+8) -> A fetched 2x (32MB),
// B fetched 4x (48MB); was A 8x (128MB) + B 1x (12MB).
__global__ __launch_bounds__(512, 2) void qkv_gemm(
    const bf16_t* __restrict__ x, const bf16_t* __restrict__ W,
    bf16_t* __restrict__ qo, bf16_t* __restrict__ ko, bf16_t* __restrict__ vo) {
  __shared__ __align__(16) bf16_t As[2][256 * 64];
  __shared__ __align__(16) bf16_t Bs[2][192 * 64];
  const int bid = blockIdx.x;
  const int xi = bid & 7, xj = bid >> 3;
  const int m0 = (((xi & 3) << 2) + (xj & 3)) * 256;
  const int n0 = (((xi >> 2) << 3) + (xj >> 2)) * 192;
  f32x4 acc[8][3] = {};
  gemm256x192_loop(x, W, 2048, m0, n0, As, Bs, acc);
  const int lane = threadIdx.x & 63, wid = threadIdx.x >> 6;
  const int quad = lane >> 4, l16 = lane & 15;
  const int am = (wid >> 2) * 128, bn = (wid & 3) * 48;
#pragma unroll
  for (int mf = 0; mf < 8; ++mf)
#pragma unroll
    for (int nf = 0; nf < 3; ++nf) {
      int gcb = n0 + bn + nf * 16;   // wave-uniform 16-aligned column base
      bf16_t* O;
      int Hn, gcl;
      if (gcb < 2048)      { O = qo; Hn = 16; gcl = gcb; }
      else if (gcb < 2560) { O = ko; Hn = 4;  gcl = gcb - 2048; }
      else                 { O = vo; Hn = 4;  gcl = gcb - 2560; }
      int gc = gcl + l16;
      int hh = gc >> 7, dd = gc & 127;
#pragma unroll
      for (int r = 0; r < 4; ++r) {
        int gr = m0 + am + mf * 16 + quad * 4 + r;
        int bb = gr >> 11, ss = gr & 2047;
        O[(((size_t)bb * Hn + hh) * 2048 + ss) * 128 + dd] = (bf16_t)acc[mf][nf][r];
      }
    }
}

// ---------- 128x256-tile counted-vmcnt loop (out): full-chip grid ----------
// 512 thr = 8 waves (2M x 4N), wave tile 64x64, BK=64, dbuf LDS 96KB.
// Regions: A+B0 (read P0), B1 (read P1). Group g stages tile t+2: A+B0 at P1,
// B1 after post-P1 barrier. Swap waits vmcnt(6); drain at tail.
__device__ __forceinline__ void gemm128x256_loop(const bf16_t* __restrict__ A,
                                                 const bf16_t* __restrict__ B,
                                                 int K, int m0, int n0,
                                                 bf16_t (*As)[128 * 64],
                                                 bf16_t (*Bs)[256 * 64],
                                                 f32x4 (&acc)[4][4]) {
  const int tid = threadIdx.x;
  const int lane = tid & 63, wid = tid >> 6;
  const int quad = lane >> 4, l16 = lane & 15;
  const int am = (wid >> 2) * 64;    // 2 M-halves of 64
  const int bn = (wid & 3) * 64;     // 4 N-quarters of 64
  const int NT = K >> 6;

  auto stageA = [&](int t, int wb) {
#pragma unroll
    for (int i2 = 0; i2 < 2; ++i2) {
      int i = i2 * 512 + tid;
      int r = i >> 3, ch = i & 7;
      int sc = ch ^ (r & 7);
      LDSCP16(A + (size_t)(m0 + r) * K + (size_t)t * 64 + sc * 8,
              (bf16_t*)As[wb] + (size_t)r * 64 + ch * 8);
    }
  };
  auto stageB = [&](int t, int wb, int off) {
#pragma unroll
    for (int i2 = 0; i2 < 2; ++i2) {
      int i = i2 * 512 + tid;
      int r = i >> 3, ch = i & 7;
      int row = (r & 31) + ((r >> 5) << 6) + off;
      int sc = ch ^ (row & 7);
      LDSCP16(B + (size_t)(n0 + row) * K + (size_t)t * 64 + sc * 8,
              (bf16_t*)Bs[wb] + (size_t)row * 64 + ch * 8);
    }
  };

  stageA(0, 0); stageB(0, 0, 0); stageB(0, 0, 32);
  stageA(1, 1); stageB(1, 1, 0); stageB(1, 1, 32);
  asm volatile("s_waitcnt vmcnt(6)" ::: "memory");
  __builtin_amdgcn_s_barrier();

  bf16x8 af[4][2], bfr[4][2];

  auto group = [&](int g, const int rb) {
    const char* Ab = (const char*)As[rb];
    const char* Bb = (const char*)Bs[rb];
    const bool pf = (g + 2 < NT);

    // ---- P0: ds_read af (8) + bfr[nf0-1] (4) ----
#pragma unroll
    for (int mf = 0; mf < 4; ++mf)
#pragma unroll
      for (int kk = 0; kk < 2; ++kk) {
        int ra = am + mf * 16 + l16;
        af[mf][kk] = *(const bf16x8*)(Ab + ra * 128 +
                                      (((kk * 4 + quad) ^ (ra & 7)) << 4));
      }
#pragma unroll
    for (int nf = 0; nf < 2; ++nf)
#pragma unroll
      for (int kk = 0; kk < 2; ++kk) {
        int rn = bn + nf * 16 + l16;
        bfr[nf][kk] = *(const bf16x8*)(Bb + rn * 128 +
                                       (((kk * 4 + quad) ^ (rn & 7)) << 4));
      }
    __builtin_amdgcn_s_barrier();
    __builtin_amdgcn_sched_barrier(0);
    __builtin_amdgcn_s_setprio(1);
#pragma unroll
    for (int kk = 0; kk < 2; ++kk)
#pragma unroll
      for (int mf = 0; mf < 4; ++mf)
#pragma unroll
        for (int nf = 0; nf < 2; ++nf)
          acc[mf][nf] = __builtin_amdgcn_mfma_f32_16x16x32_bf16(
              af[mf][kk], bfr[nf][kk], acc[mf][nf], 0, 0, 0);
    __builtin_amdgcn_s_setprio(0);
    __builtin_amdgcn_sched_barrier(0);
    __builtin_amdgcn_s_barrier();
    __builtin_amdgcn_sched_barrier(0);

    // ---- P1: ds_read bfr[nf2-3] (4); stage A(t+2)+B0(t+2) ----
#pragma unroll
    for (int nf = 2; nf < 4; ++nf)
#pragma unroll
      for (int kk = 0; kk < 2; ++kk) {
        int rn = bn + nf * 16 + l16;
        bfr[nf][kk] = *(const bf16x8*)(Bb + rn * 128 +
                                       (((kk * 4 + quad) ^ (rn & 7)) << 4));
      }
    if (pf) { stageA(g + 2, rb); stageB(g + 2, rb, 0); }
    __builtin_amdgcn_s_barrier();
    __builtin_amdgcn_sched_barrier(0);
    __builtin_amdgcn_s_setprio(1);
#pragma unroll
    for (int kk = 0; kk < 2; ++kk)
#pragma unroll
      for (int mf = 0; mf < 4; ++mf)
#pragma unroll
        for (int nf = 2; nf < 4; ++nf)
          acc[mf][nf] = __builtin_amdgcn_mfma_f32_16x16x32_bf16(
              af[mf][kk], bfr[nf][kk], acc[mf][nf], 0, 0, 0);
    __builtin_amdgcn_s_setprio(0);
    __builtin_amdgcn_sched_barrier(0);
    __builtin_amdgcn_s_barrier();   // all waves' P1 MFMAs issued => B1 reads done
    __builtin_amdgcn_sched_barrier(0);

    // ---- tail: stage B1(t+2); counted swap wait ----
    if (pf) stageB(g + 2, rb, 32);
    __builtin_amdgcn_sched_barrier(0);
    if (g + 2 < NT)      asm volatile("s_waitcnt vmcnt(6)" ::: "memory");
    else if (g + 1 < NT) asm volatile("s_waitcnt vmcnt(0)" ::: "memory");
    __builtin_amdgcn_s_barrier();
  };

  for (int g2 = 0; g2 < NT; g2 += 2) {
    group(g2, 0);
    group(g2 + 1, 1);
  }
}

// ---------- output projection: out = ctx(bf16) * Wo(bf16)^T, fp32 out --------
// 1D grid 256 with XCD m-band swizzle: XCD i owns m-rows [4i,4i+4) x all n ->
// A fetched once (16MB) + B 8x (64MB); was A 8x (128MB) + B 1x (8MB).
__global__ __launch_bounds__(512, 2) void out_gemm(const bf16_t* __restrict__ ctx,
                                                   const bf16_t* __restrict__ Wo,
                                                   float* __restrict__ out) {
  __shared__ __align__(16) bf16_t As[2][128 * 64];
  __shared__ __align__(16) bf16_t Bs[2][256 * 64];
  const int bid = blockIdx.x;
  const int xi = bid & 7, xj = bid >> 3;
  const int m0 = ((xi << 2) + (xj & 3)) * 128;
  const int n0 = (xj >> 2) * 256;
  f32x4 acc[4][4] = {};
  gemm128x256_loop(ctx, Wo, 2048, m0, n0, As, Bs, acc);
  const int lane = threadIdx.x & 63, wid = threadIdx.x >> 6;
  const int quad = lane >> 4, l16 = lane & 15;
  const int am = (wid >> 2) * 64, bn = (wid & 3) * 64;
#pragma unroll
  for (int mf = 0; mf < 4; ++mf)
#pragma unroll
    for (int nf = 0; nf < 4; ++nf)
#pragma unroll
      for (int r = 0; r < 4; ++r) {
        int gr = m0 + am + mf * 16 + quad * 4 + r;
        int gc = n0 + bn + nf * 16 + l16;
        out[(size_t)gr * 2048 + gc] = acc[mf][nf][r];
      }
}

// ---------- fused mid-stage: RMSNorm+RoPE (k only) | V transpose | Wo cast ---
// q moved into attn prologue (R21). blocks [0,4096): k rows;
// [4096,4608): vtrans; [4608,6656): Wo fp32->bf16 cast.
__global__ __launch_bounds__(256) void mid_fused(
    bf16_t* __restrict__ kx, const float* __restrict__ kw,
    const float* __restrict__ cs, const float* __restrict__ sn,
    const bf16_t* __restrict__ v, bf16_t* __restrict__ vt,
    const float* __restrict__ wo, bf16_t* __restrict__ wob) {
  __shared__ bf16_t t[64][72];
  const int blk = blockIdx.x;
  const int tid = threadIdx.x;
  if (blk < 4096) {
    // ---- k RMSNorm + RoPE, one wave per row ----
    int row = blk * 4 + (tid >> 6);
    const int lane = tid & 63;
    const int pos = row & 2047;
    bf16_t* p = kx + (size_t)row * 128;
    float v1 = (float)p[lane];
    float v2 = (float)p[lane + 64];
    float ss = v1 * v1 + v2 * v2;
#pragma unroll
    for (int m = 32; m; m >>= 1) ss += __shfl_xor(ss, m);
    float rr = rsqrtf(ss * (1.0f / 128.0f) + 1e-6f);
    float n1 = v1 * rr * kw[lane];
    float n2 = v2 * rr * kw[lane + 64];
    float c1 = cs[pos * 128 + lane],      s1 = sn[pos * 128 + lane];
    float c2 = cs[pos * 128 + lane + 64], s2 = sn[pos * 128 + lane + 64];
    p[lane]      = (bf16_t)(n1 * c1 - n2 * s1);
    p[lane + 64] = (bf16_t)(n2 * c2 + n1 * s2);
  } else if (blk < 4608) {
    // ---- V transpose: [BG,S,HD] -> [BG,HD,S], 64x64 tile ----
    const int vv = blk - 4096;
    const int t0 = (vv & 31) * 64, d0 = ((vv >> 5) & 1) * 64, bg = vv >> 6;
    const int r = tid >> 3, c = (tid & 7) * 8;
    const bf16_t* src = v + ((size_t)bg * 2048 + t0) * 128 + d0;
#pragma unroll
    for (int it = 0; it < 2; ++it) {
      uint4 val = *(const uint4*)(src + (size_t)(r + it * 32) * 128 + c);
      *(uint4*)&t[r + it * 32][c] = val;
    }
    __syncthreads();
#pragma unroll
    for (int it = 0; it < 2; ++it) {
      int d = r + it * 32;
      bf16_t tmp[8];
#pragma unroll
      for (int j = 0; j < 8; ++j) tmp[j] = t[c + j][d];
      *(uint4*)(vt + ((size_t)bg * 128 + d0 + d) * 2048 + t0 + c) = *(uint4*)tmp;
    }
  } else {
    // ---- Wo fp32 -> bf16 ----
    size_t i = (size_t)(blk - 4608) * 256 + tid;
    const float* g = wo + i * 8;
    f32x4 u0 = *(const f32x4*)g;
    f32x4 u1 = *(const f32x4*)(g + 4);
    bf16x8 vv8;
    vv8[0] = (bf16_t)u0[0]; vv8[1] = (bf16_t)u0[1]; vv8[2] = (bf16_t)u0[2]; vv8[3] = (bf16_t)u0[3];
    vv8[4] = (bf16_t)u1[0]; vv8[5] = (bf16_t)u1[1]; vv8[6] = (bf16_t)u1[2]; vv8[7] = (bf16_t)u1[3];
    *(bf16x8*)(wob + i * 8) = vv8;
  }
}

// ---------- flash attention: GQA head-merged, uniform blocks, transposed QK --
// R18 loop (FROZEN) + fused q RMSNorm/RoPE/scale in the Q-prologue (reads RAW
// qb). Lane holds cols {kk*32+quad*8+j}; RoPE pair c<->c+64 is kk<->kk+2
// (lane-local); RMS sum reduces over quad group via shfl_xor(16,32). Same
// bf16 rounding point as the old mid_fused path. 1D grid 512: qi=bid>>3,
// gb=bid&7 -> one (g,b) K/V stream per XCD. Fixed-base softmax (qscale =
// HD^-0.5*log2e folded into normalized q).
__global__ __launch_bounds__(256) void attn_kernel(const bf16_t* __restrict__ q,
    const bf16_t* __restrict__ k, const bf16_t* __restrict__ vt,
    bf16_t* __restrict__ ctx, const float* __restrict__ qw,
    const float* __restrict__ cs, const float* __restrict__ sn, float qscale) {
  __shared__ __align__(16) char Plds[2][4][2048];  // [pb][h][16 rows x 128B]
  __shared__ __align__(16) float lred[4][16][4];
  const int bid = blockIdx.x;
  const int qi = bid >> 3, gb = bid & 7;
  const int g = gb & 3, b = gb >> 2;
  const int tid = threadIdx.x, w = tid >> 6, lane = tid & 63;
  const int quad = lane >> 4, l16 = lane & 15;
  const bf16_t* kp = k + ((size_t)b * 4 + g) * 2048 * 128 +
                     (size_t)(w * 16 + l16) * 128 + quad * 8;
  const bf16_t* vp = vt + ((size_t)b * 4 + g) * 128 * 2048 +
                     (size_t)(w * 32 + l16) * 2048 + quad * 8;

#pragma unroll 1
  for (int ph = 0; ph < 2; ++ph) {
    const int qt = ph ? 127 - qi : qi;

    // Q A-fragments: 16 rows (m=l16) per head (64 VGPR), RAW from qb
    bf16x8 qf[4][4];
#pragma unroll
    for (int h = 0; h < 4; ++h)
#pragma unroll
      for (int kk = 0; kk < 4; ++kk)
        qf[h][kk] = *(const bf16x8*)(q +
            (((size_t)b * 16 + g * 4 + h) * 2048 + (size_t)qt * 16 + l16) * 128 +
            kk * 32 + quad * 8);

    // ---- fused q RMSNorm + RoPE + qscale (in place on qf) ----
    {
      const int pos = qt * 16 + l16;
      const float* cpr = cs + (size_t)pos * 128;
      const float* spr = sn + (size_t)pos * 128;
      float rr[4];
#pragma unroll
      for (int h = 0; h < 4; ++h) {
        float ss = 0.f;
#pragma unroll
        for (int kk = 0; kk < 4; ++kk)
#pragma unroll
          for (int j = 0; j < 8; ++j) {
            float vv = (float)qf[h][kk][j];
            ss += vv * vv;
          }
        ss += __shfl_xor(ss, 16);
        ss += __shfl_xor(ss, 32);
        rr[h] = rsqrtf(ss * (1.0f / 128.0f) + 1e-6f) * qscale;
      }
#pragma unroll
      for (int p = 0; p < 2; ++p) {      // pair kk=p (c<64) with kk=p+2 (c+64)
        const int cl = p * 32 + quad * 8;
        const int chh = cl + 64;
        float wl[8], wh[8], col_[8], coh[8], sil[8], sih[8];
        *(f32x4*)&wl[0]   = *(const f32x4*)(qw + cl);
        *(f32x4*)&wl[4]   = *(const f32x4*)(qw + cl + 4);
        *(f32x4*)&wh[0]   = *(const f32x4*)(qw + chh);
        *(f32x4*)&wh[4]   = *(const f32x4*)(qw + chh + 4);
        *(f32x4*)&col_[0] = *(const f32x4*)(cpr + cl);
        *(f32x4*)&col_[4] = *(const f32x4*)(cpr + cl + 4);
        *(f32x4*)&coh[0]  = *(const f32x4*)(cpr + chh);
        *(f32x4*)&coh[4]  = *(const f32x4*)(cpr + chh + 4);
        *(f32x4*)&sil[0]  = *(const f32x4*)(spr + cl);
        *(f32x4*)&sil[4]  = *(const f32x4*)(spr + cl + 4);
        *(f32x4*)&sih[0]  = *(const f32x4*)(spr + chh);
        *(f32x4*)&sih[4]  = *(const f32x4*)(spr + chh + 4);
#pragma unroll
        for (int h = 0; h < 4; ++h) {
          bf16x8 outl, outh;
#pragma unroll
          for (int j = 0; j < 8; ++j) {
            float nl = (float)qf[h][p][j]     * rr[h] * wl[j];
            float nh = (float)qf[h][p + 2][j] * rr[h] * wh[j];
            outl[j] = (bf16_t)(nl * col_[j] - nh * sil[j]);
            outh[j] = (bf16_t)(nh * coh[j] + nl * sih[j]);
          }
          qf[h][p] = outl;
          qf[h][p + 2] = outh;
        }
      }
    }

    f32x4 oacc[4][2] = {};
    float lsum[4] = {};
    const int nkt = (qt >> 2) + 1;
    for (int kt = 0; kt < nkt; ++kt) {
      // K fragments (A-operand of S^T: m = kcol w*16+l16), one fetch, 4 heads
      const bf16_t* kro = kp + (size_t)kt * 64 * 128;
      bf16x8 kf[4];
#pragma unroll
      for (int kk = 0; kk < 4; ++kk) kf[kk] = *(const bf16x8*)(kro + kk * 32);
      // V fragments (B-layout n=l16 -> d = w*32+nd*16+l16), used after barrier
      const bf16_t* vro = vp + (size_t)kt * 64;
      bf16x8 vf[2][2];
#pragma unroll
      for (int nd = 0; nd < 2; ++nd)
#pragma unroll
        for (int kkp = 0; kkp < 2; ++kkp)
          vf[nd][kkp] = *(const bf16x8*)(vro + (size_t)nd * 16 * 2048 + kkp * 32);

      // S^T = K Q^T: C row = kcol_local (quad*4+r), col = qrow_local (l16)
      f32x4 sacc[4] = {};
#pragma unroll
      for (int kk = 0; kk < 4; ++kk)
#pragma unroll
        for (int h = 0; h < 4; ++h)
          sacc[h] = __builtin_amdgcn_mfma_f32_16x16x32_bf16(kf[kk], qf[h][kk],
                                                            sacc[h], 0, 0, 0);
      if (kt == nkt - 1) {  // diagonal tile: mask kcol > qrow
        int kcol = kt * 64 + w * 16 + quad * 4;
        int qrow = qt * 16 + l16;
#pragma unroll
        for (int r = 0; r < 4; ++r)
          if (kcol + r > qrow)
#pragma unroll
            for (int h = 0; h < 4; ++h) sacc[h][r] = -1e30f;
      }

      // softmax numerator + packed 8B P-write (row = qrow l16, 4 consec kcols)
      const int pb = kt & 1;
      const int c0 = w * 2 + (quad >> 1);
      const int woff = l16 * 128 + ((c0 ^ (l16 & 7)) << 4) + ((quad & 1) << 3);
#pragma unroll
      for (int h = 0; h < 4; ++h) {
        float p0 = __builtin_amdgcn_exp2f(sacc[h][0]);
        float p1 = __builtin_amdgcn_exp2f(sacc[h][1]);
        float p2 = __builtin_amdgcn_exp2f(sacc[h][2]);
        float p3 = __builtin_amdgcn_exp2f(sacc[h][3]);
        lsum[h] += (p0 + p1) + (p2 + p3);
        bf16x4 pk;
        pk[0] = (bf16_t)p0; pk[1] = (bf16_t)p1; pk[2] = (bf16_t)p2; pk[3] = (bf16_t)p3;
        *(bf16x4*)(Plds[pb][h] + woff) = pk;
      }
      __syncthreads();  // the only barrier in the loop

      // O += P * V: A = P (m=qrow l16, k=kcol quad*8+j), B = V^T
#pragma unroll
      for (int kkp = 0; kkp < 2; ++kkp) {
        bf16x8 pf[4];
#pragma unroll
        for (int h = 0; h < 4; ++h)
          pf[h] = *(const bf16x8*)(Plds[pb][h] + l16 * 128 +
                                   (((kkp * 4 + quad) ^ (l16 & 7)) << 4));
#pragma unroll
        for (int nd = 0; nd < 2; ++nd)
#pragma unroll
          for (int h = 0; h < 4; ++h)
            oacc[h][nd] = __builtin_amdgcn_mfma_f32_16x16x32_bf16(
                pf[h], vf[nd][kkp], oacc[h][nd], 0, 0, 0);
      }
    }

    // row-sum: lane's lsum covers its 4 kcols at qrow=l16; reduce across quads
    // (lanes l16, l16+16, l16+32, l16+48) then across waves via LDS.
#pragma unroll
    for (int h = 0; h < 4; ++h) {
      float v = lsum[h];
      v += __shfl_xor(v, 16);
      v += __shfl_xor(v, 32);
      if (quad == 0) lred[h][l16][w] = v;
    }
    __syncthreads();
    // epilogue: oacc C-layout row = qrow_local quad*4+r, col = d_local l16
#pragma unroll
    for (int h = 0; h < 4; ++h)
#pragma unroll
      for (int r = 0; r < 4; ++r) {
        int row = quad * 4 + r;
        f32x4 t = *(const f32x4*)lred[h][row];
        float inv = 1.f / (t[0] + t[1] + t[2] + t[3]);
        int pos = qt * 16 + row;
        size_t base = (((size_t)b * 2048 + pos) * 16 + g * 4 + h) * 128;
#pragma unroll
        for (int nd = 0; nd < 2; ++nd)
          ctx[base + w * 32 + nd * 16 + l16] = (bf16_t)(oacc[h][nd][r] * inv);
      }
  }
}

extern "C" void kernel_launch(void* const* d_in, const int* in_sizes, int n_in,
                              void* d_out, int out_size, void* d_ws, size_t ws_size,
                              hipStream_t stream) {
  (void)in_sizes; (void)n_in; (void)out_size; (void)ws_size;
  const float* x    = (const float*)d_in[0];
  const float* cosp = (const float*)d_in[2];
  const float* sinp = (const float*)d_in[3];
  const float* Wq   = (const float*)d_in[4];
  const float* Wk   = (const float*)d_in[5];
  const float* Wv   = (const float*)d_in[6];
  const float* Wo   = (const float*)d_in[7];
  const float* qnw  = (const float*)d_in[8];
  const float* knw  = (const float*)d_in[9];
  float* out = (float*)d_out;

  char* ws = (char*)d_ws;
  bf16_t* qb  = (bf16_t*)(ws);               // 16777216 B
  bf16_t* kb  = (bf16_t*)(ws + 16777216);    //  4194304 B
  bf16_t* vb  = (bf16_t*)(ws + 20971520);    //  4194304 B
  bf16_t* vtb = (bf16_t*)(ws + 25165824);    //  4194304 B
  bf16_t* ctx = (bf16_t*)(ws + 29360128);    // 16777216 B
  bf16_t* xb  = (bf16_t*)(ws + 29360128);    // aliases ctx (dead before attn)
  bf16_t* wqb = (bf16_t*)(ws + 46137344);    //  8388608 B — contiguous with
  bf16_t* wob = (bf16_t*)(ws + 46137344);    //  wkb/wvb => [3072,2048] W
  bf16_t* wkb = (bf16_t*)(ws + 54525952);    //  2097152 B
  bf16_t* wvb = (bf16_t*)(ws + 56623104);    //  2097152 B

  cast_all<<<7168, 256, 0, stream>>>(x, Wq, Wk, Wv, xb, wqb, wkb, wvb);
  qkv_gemm<<<256, 512, 0, stream>>>(xb, wqb, qb, kb, vb);
  mid_fused<<<6656, 256, 0, stream>>>(kb, knw, cosp, sinp, vb, vtb, Wo, wob);
  // q scale = HD^-0.5 * log2(e) folded for fixed-base exp2 softmax (in attn)
  attn_kernel<<<512, 256, 0, stream>>>(qb, kb, vtb, ctx, qnw, cosp, sinp,
                                       0.12751742902f);
  out_gemm<<<256, 512, 0, stream>>>(ctx, wob, out);
}

// Round 13
// 314.354 us; speedup vs baseline: 1.0298x; 1.0298x over previous
//
#include <hip/hip_runtime.h>
#include <hip/hip_bf16.h>

// GroupedQueryAttention: B=2,S=2048,D=2048,H=16,G=4,HD=128, causal, rmsnorm+rope.
// Inputs fp32; OUTPUT fp32. Internal compute bf16 MFMA / fp32 accumulate.
// R22: verified-parts assembly. attn = R20/R18 exact (81.4us; R21's Q-fusion
// raised VGPR 112->156, halved residency, +20us -> reverted; attn experiments
// CLOSED). mid_fused = R20 full (q+k rmsnorm/rope). qkv/out keep R21's XCD
// swizzles (rest-of-pipeline -15.8us measured).
// ws (58.7 MB): qb | kb | vb | vtb | ctx(=xb alias) | wqb(=wob) | wkb | wvb

typedef __bf16 bf16_t;
using bf16x4 = __attribute__((ext_vector_type(4))) __bf16;
using bf16x8 = __attribute__((ext_vector_type(8))) __bf16;
using f32x4  = __attribute__((ext_vector_type(4))) float;

#define LDSCP16(gp, lp)                                                       \
  __builtin_amdgcn_global_load_lds(                                           \
      (__attribute__((address_space(1))) void*)(gp),                          \
      (__attribute__((address_space(3))) void*)(lp), 16, 0, 0)

// ---------- merged fp32 -> bf16 casts: x | Wq | Wk | Wv ----------
__global__ __launch_bounds__(256) void cast_all(
    const float* __restrict__ x, const float* __restrict__ wq,
    const float* __restrict__ wk, const float* __restrict__ wv,
    bf16_t* __restrict__ xb, bf16_t* __restrict__ wqb,
    bf16_t* __restrict__ wkb, bf16_t* __restrict__ wvb) {
  int blk = blockIdx.x;
  const float* s;
  bf16_t* d;
  size_t base;
  if (blk < 4096)      { s = x;  d = xb;  base = blk; }
  else if (blk < 6144) { s = wq; d = wqb; base = blk - 4096; }
  else if (blk < 6656) { s = wk; d = wkb; base = blk - 6144; }
  else                 { s = wv; d = wvb; base = blk - 6656; }
  size_t i = base * 256 + threadIdx.x;
  const float* g = s + i * 8;
  f32x4 u0 = *(const f32x4*)g;
  f32x4 u1 = *(const f32x4*)(g + 4);
  bf16x8 v;
  v[0] = (bf16_t)u0[0]; v[1] = (bf16_t)u0[1]; v[2] = (bf16_t)u0[2]; v[3] = (bf16_t)u0[3];
  v[4] = (bf16_t)u1[0]; v[5] = (bf16_t)u1[1]; v[6] = (bf16_t)u1[2]; v[7] = (bf16_t)u1[3];
  *(bf16x8*)(d + i * 8) = v;
}

// ---------- 256x192-tile counted-vmcnt GEMM mainloop (qkv): C = A*B^T -------
// 512 thr = 8 waves (2M x 4N), wave tile 128x48, BK=64, dbuf LDS 112KB.
// B = contiguous [3072,2048] (Wq|Wk|Wv). 7 load-units/K-tile (A 4, B 3).
// Read regions: P0 = A{0-63,128-191} + B{0-31,48-79,96-127,144-175};
// P1 = B{32-47,80-95,128-143,176-191}; P2 = A{64-127,192-255}.
// Group g stages tile t+2 into its OWN buffer one phase after each region's
// reads complete (P1: A-half0+B0, P2: B1, P3: A-half1). Swap waits vmcnt(7)
// (this group's 7 loads in flight; tile t+1 landed). Drain only at tail.
__device__ __forceinline__ void gemm256x192_loop(const bf16_t* __restrict__ A,
                                                 const bf16_t* __restrict__ B,
                                                 int K, int m0, int n0,
                                                 bf16_t (*As)[256 * 64],
                                                 bf16_t (*Bs)[192 * 64],
                                                 f32x4 (&acc)[8][3]) {
  const int tid = threadIdx.x;
  const int lane = tid & 63, wid = tid >> 6;
  const int quad = lane >> 4, l16 = lane & 15;
  const int am = (wid >> 2) * 128;   // wave's A-row base (2 M-halves)
  const int bn = (wid & 3) * 48;     // wave's B-row base (4 N-quarters of 48)
  const int NT = K >> 6;

  // A-region (2 units): rows (r&63) + (r>>6)*128 + off (off=0 or 64)
  auto stageA = [&](int t, int wb, int off) {
#pragma unroll
    for (int i2 = 0; i2 < 2; ++i2) {
      int i = i2 * 512 + tid;
      int r = i >> 3, ch = i & 7;
      int row = (r & 63) + ((r >> 6) << 7) + off;
      int sc = ch ^ (row & 7);
      LDSCP16(A + (size_t)(m0 + row) * K + (size_t)t * 64 + sc * 8,
              (bf16_t*)As[wb] + (size_t)row * 64 + ch * 8);
    }
  };
  // B0 (2 units): rows (r&31) + (r>>5)*48 -> {0-31,48-79,96-127,144-175}
  auto stageB0 = [&](int t, int wb) {
#pragma unroll
    for (int i2 = 0; i2 < 2; ++i2) {
      int i = i2 * 512 + tid;
      int r = i >> 3, ch = i & 7;
      int row = (r & 31) + (r >> 5) * 48;
      int sc = ch ^ (row & 7);
      LDSCP16(B + (size_t)(n0 + row) * K + (size_t)t * 64 + sc * 8,
              (bf16_t*)Bs[wb] + (size_t)row * 64 + ch * 8);
    }
  };
  // B1 (1 unit): rows 32 + (r&15) + (r>>4)*48 -> {32-47,80-95,128-143,176-191}
  auto stageB1 = [&](int t, int wb) {
    int r = tid >> 3, ch = tid & 7;
    int row = 32 + (r & 15) + (r >> 4) * 48;
    int sc = ch ^ (row & 7);
    LDSCP16(B + (size_t)(n0 + row) * K + (size_t)t * 64 + sc * 8,
            (bf16_t*)Bs[wb] + (size_t)row * 64 + ch * 8);
  };

  // prologue: tile0 -> buf0, tile1 -> buf1 (7 loads each); wait tile0.
  stageA(0, 0, 0); stageB0(0, 0); stageB1(0, 0); stageA(0, 0, 64);
  stageA(1, 1, 0); stageB0(1, 1); stageB1(1, 1); stageA(1, 1, 64);
  asm volatile("s_waitcnt vmcnt(7)" ::: "memory");
  __builtin_amdgcn_s_barrier();

  bf16x8 af[4][2], bfr[3][2];

  auto group = [&](int g, const int rb) {
    const char* Ab = (const char*)As[rb];
    const char* Bb = (const char*)Bs[rb];
    const bool pf = (g + 2 < NT);

    // ---- P0: ds_read af[mf0-3] (8) + bfr[nf0-1] (4); no staging ----
#pragma unroll
    for (int mf = 0; mf < 4; ++mf)
#pragma unroll
      for (int kk = 0; kk < 2; ++kk) {
        int ra = am + mf * 16 + l16;
        af[mf][kk] = *(const bf16x8*)(Ab + ra * 128 +
                                      (((kk * 4 + quad) ^ (ra & 7)) << 4));
      }
#pragma unroll
    for (int nf = 0; nf < 2; ++nf)
#pragma unroll
      for (int kk = 0; kk < 2; ++kk) {
        int rn = bn + nf * 16 + l16;
        bfr[nf][kk] = *(const bf16x8*)(Bb + rn * 128 +
                                       (((kk * 4 + quad) ^ (rn & 7)) << 4));
      }
    __builtin_amdgcn_s_barrier();
    __builtin_amdgcn_sched_barrier(0);
    __builtin_amdgcn_s_setprio(1);
#pragma unroll
    for (int kk = 0; kk < 2; ++kk)
#pragma unroll
      for (int mf = 0; mf < 4; ++mf)
#pragma unroll
        for (int nf = 0; nf < 2; ++nf)
          acc[mf][nf] = __builtin_amdgcn_mfma_f32_16x16x32_bf16(
              af[mf][kk], bfr[nf][kk], acc[mf][nf], 0, 0, 0);
    __builtin_amdgcn_s_setprio(0);
    __builtin_amdgcn_sched_barrier(0);
    __builtin_amdgcn_s_barrier();
    __builtin_amdgcn_sched_barrier(0);

    // ---- P1: ds_read bfr[nf2] (2); stage A-half0 + B0 of t+2 (4) ----
#pragma unroll
    for (int kk = 0; kk < 2; ++kk) {
      int rn = bn + 32 + l16;
      bfr[2][kk] = *(const bf16x8*)(Bb + rn * 128 +
                                    (((kk * 4 + quad) ^ (rn & 7)) << 4));
    }
    if (pf) { stageA(g + 2, rb, 0); stageB0(g + 2, rb); }
    __builtin_amdgcn_s_barrier();
    __builtin_amdgcn_sched_barrier(0);
    __builtin_amdgcn_s_setprio(1);
#pragma unroll
    for (int kk = 0; kk < 2; ++kk)
#pragma unroll
      for (int mf = 0; mf < 4; ++mf)
        acc[mf][2] = __builtin_amdgcn_mfma_f32_16x16x32_bf16(
            af[mf][kk], bfr[2][kk], acc[mf][2], 0, 0, 0);
    __builtin_amdgcn_s_setprio(0);
    __builtin_amdgcn_sched_barrier(0);
    __builtin_amdgcn_s_barrier();
    __builtin_amdgcn_sched_barrier(0);

    // ---- P2: ds_read af[mf4-7] (8, regs reused); stage B1(t+2) (1) ----
#pragma unroll
    for (int mf = 0; mf < 4; ++mf)
#pragma unroll
      for (int kk = 0; kk < 2; ++kk) {
        int ra = am + 64 + mf * 16 + l16;
        af[mf][kk] = *(const bf16x8*)(Ab + ra * 128 +
                                      (((kk * 4 + quad) ^ (ra & 7)) << 4));
      }
    if (pf) stageB1(g + 2, rb);
    __builtin_amdgcn_s_barrier();
    __builtin_amdgcn_sched_barrier(0);
    __builtin_amdgcn_s_setprio(1);
#pragma unroll
    for (int kk = 0; kk < 2; ++kk)
#pragma unroll
      for (int mf = 0; mf < 4; ++mf)
        acc[mf + 4][2] = __builtin_amdgcn_mfma_f32_16x16x32_bf16(
            af[mf][kk], bfr[2][kk], acc[mf + 4][2], 0, 0, 0);
    __builtin_amdgcn_s_setprio(0);
    __builtin_amdgcn_sched_barrier(0);
    __builtin_amdgcn_s_barrier();
    __builtin_amdgcn_sched_barrier(0);

    // ---- P3: stage A-half1(t+2) (2); MFMA mf4-7 x nf0-1 (reg-only); swap ----
    if (pf) stageA(g + 2, rb, 64);
    __builtin_amdgcn_sched_barrier(0);
    __builtin_amdgcn_s_setprio(1);
#pragma unroll
    for (int kk = 0; kk < 2; ++kk)
#pragma unroll
      for (int mf = 0; mf < 4; ++mf)
#pragma unroll
        for (int nf = 0; nf < 2; ++nf)
          acc[mf + 4][nf] = __builtin_amdgcn_mfma_f32_16x16x32_bf16(
              af[mf][kk], bfr[nf][kk], acc[mf + 4][nf], 0, 0, 0);
    __builtin_amdgcn_s_setprio(0);
    __builtin_amdgcn_sched_barrier(0);
    if (g + 2 < NT)      asm volatile("s_waitcnt vmcnt(7)" ::: "memory");
    else if (g + 1 < NT) asm volatile("s_waitcnt vmcnt(0)" ::: "memory");
    __builtin_amdgcn_s_barrier();
  };

  for (int g2 = 0; g2 < NT; g2 += 2) {
    group(g2, 0);
    group(g2 + 1, 1);
  }
}

// ---------- fused QKV projection; writes head-major [B,Hn,S,HD] bf16 ----------
// B = contiguous Wq|Wk|Wv [3072,2048]; 1D grid 256 with XCD region swizzle:
// XCD i owns m-rows [4(i&3),+4) x n-cols [8(i>>2),+8) -> A fetched 2x (32MB),
// B fetched 4x (48MB); was A 8x (128MB) + B 1x (12MB).
__global__ __launch_bounds__(512, 2) void qkv_gemm(
    const bf16_t* __restrict__ x, const bf16_t* __restrict__ W,
    bf16_t* __restrict__ qo, bf16_t* __restrict__ ko, bf16_t* __restrict__ vo) {
  __shared__ __align__(16) bf16_t As[2][256 * 64];
  __shared__ __align__(16) bf16_t Bs[2][192 * 64];
  const int bid = blockIdx.x;
  const int xi = bid & 7, xj = bid >> 3;
  const int m0 = (((xi & 3) << 2) + (xj & 3)) * 256;
  const int n0 = (((xi >> 2) << 3) + (xj >> 2)) * 192;
  f32x4 acc[8][3] = {};
  gemm256x192_loop(x, W, 2048, m0, n0, As, Bs, acc);
  const int lane = threadIdx.x & 63, wid = threadIdx.x >> 6;
  const int quad = lane >> 4, l16 = lane & 15;
  const int am = (wid >> 2) * 128, bn = (wid & 3) * 48;
#pragma unroll
  for (int mf = 0; mf < 8; ++mf)
#pragma unroll
    for (int nf = 0; nf < 3; ++nf) {
      int gcb = n0 + bn + nf * 16;   // wave-uniform 16-aligned column base
      bf16_t* O;
      int Hn, gcl;
      if (gcb < 2048)      { O = qo; Hn = 16; gcl = gcb; }
      else if (gcb < 2560) { O = ko; Hn = 4;  gcl = gcb - 2048; }
      else                 { O = vo; Hn = 4;  gcl = gcb - 2560; }
      int gc = gcl + l16;
      int hh = gc >> 7, dd = gc & 127;
#pragma unroll
      for (int r = 0; r < 4; ++r) {
        int gr = m0 + am + mf * 16 + quad * 4 + r;
        int bb = gr >> 11, ss = gr & 2047;
        O[(((size_t)bb * Hn + hh) * 2048 + ss) * 128 + dd] = (bf16_t)acc[mf][nf][r];
      }
    }
}

// ---------- 128x256-tile counted-vmcnt loop (out): full-chip grid ----------
// 512 thr = 8 waves (2M x 4N), wave tile 64x64, BK=64, dbuf LDS 96KB.
// Regions: A+B0 (read P0), B1 (read P1). Group g stages tile t+2: A+B0 at P1,
// B1 after post-P1 barrier. Swap waits vmcnt(6); drain at tail.
__device__ __forceinline__ void gemm128x256_loop(const bf16_t* __restrict__ A,
                                                 const bf16_t* __restrict__ B,
                                                 int K, int m0, int n0,
                                                 bf16_t (*As)[128 * 64],
                                                 bf16_t (*Bs)[256 * 64],
                                                 f32x4 (&acc)[4][4]) {
  const int tid = threadIdx.x;
  const int lane = tid & 63, wid = tid >> 6;
  const int quad = lane >> 4, l16 = lane & 15;
  const int am = (wid >> 2) * 64;    // 2 M-halves of 64
  const int bn = (wid & 3) * 64;     // 4 N-quarters of 64
  const int NT = K >> 6;

  auto stageA = [&](int t, int wb) {
#pragma unroll
    for (int i2 = 0; i2 < 2; ++i2) {
      int i = i2 * 512 + tid;
      int r = i >> 3, ch = i & 7;
      int sc = ch ^ (r & 7);
      LDSCP16(A + (size_t)(m0 + r) * K + (size_t)t * 64 + sc * 8,
              (bf16_t*)As[wb] + (size_t)r * 64 + ch * 8);
    }
  };
  auto stageB = [&](int t, int wb, int off) {
#pragma unroll
    for (int i2 = 0; i2 < 2; ++i2) {
      int i = i2 * 512 + tid;
      int r = i >> 3, ch = i & 7;
      int row = (r & 31) + ((r >> 5) << 6) + off;
      int sc = ch ^ (row & 7);
      LDSCP16(B + (size_t)(n0 + row) * K + (size_t)t * 64 + sc * 8,
              (bf16_t*)Bs[wb] + (size_t)row * 64 + ch * 8);
    }
  };

  stageA(0, 0); stageB(0, 0, 0); stageB(0, 0, 32);
  stageA(1, 1); stageB(1, 1, 0); stageB(1, 1, 32);
  asm volatile("s_waitcnt vmcnt(6)" ::: "memory");
  __builtin_amdgcn_s_barrier();

  bf16x8 af[4][2], bfr[4][2];

  auto group = [&](int g, const int rb) {
    const char* Ab = (const char*)As[rb];
    const char* Bb = (const char*)Bs[rb];
    const bool pf = (g + 2 < NT);

    // ---- P0: ds_read af (8) + bfr[nf0-1] (4) ----
#pragma unroll
    for (int mf = 0; mf < 4; ++mf)
#pragma unroll
      for (int kk = 0; kk < 2; ++kk) {
        int ra = am + mf * 16 + l16;
        af[mf][kk] = *(const bf16x8*)(Ab + ra * 128 +
                                      (((kk * 4 + quad) ^ (ra & 7)) << 4));
      }
#pragma unroll
    for (int nf = 0; nf < 2; ++nf)
#pragma unroll
      for (int kk = 0; kk < 2; ++kk) {
        int rn = bn + nf * 16 + l16;
        bfr[nf][kk] = *(const bf16x8*)(Bb + rn * 128 +
                                       (((kk * 4 + quad) ^ (rn & 7)) << 4));
      }
    __builtin_amdgcn_s_barrier();
    __builtin_amdgcn_sched_barrier(0);
    __builtin_amdgcn_s_setprio(1);
#pragma unroll
    for (int kk = 0; kk < 2; ++kk)
#pragma unroll
      for (int mf = 0; mf < 4; ++mf)
#pragma unroll
        for (int nf = 0; nf < 2; ++nf)
          acc[mf][nf] = __builtin_amdgcn_mfma_f32_16x16x32_bf16(
              af[mf][kk], bfr[nf][kk], acc[mf][nf], 0, 0, 0);
    __builtin_amdgcn_s_setprio(0);
    __builtin_amdgcn_sched_barrier(0);
    __builtin_amdgcn_s_barrier();
    __builtin_amdgcn_sched_barrier(0);

    // ---- P1: ds_read bfr[nf2-3] (4); stage A(t+2)+B0(t+2) ----
#pragma unroll
    for (int nf = 2; nf < 4; ++nf)
#pragma unroll
      for (int kk = 0; kk < 2; ++kk) {
        int rn = bn + nf * 16 + l16;
        bfr[nf][kk] = *(const bf16x8*)(Bb + rn * 128 +
                                       (((kk * 4 + quad) ^ (rn & 7)) << 4));
      }
    if (pf) { stageA(g + 2, rb); stageB(g + 2, rb, 0); }
    __builtin_amdgcn_s_barrier();
    __builtin_amdgcn_sched_barrier(0);
    __builtin_amdgcn_s_setprio(1);
#pragma unroll
    for (int kk = 0; kk < 2; ++kk)
#pragma unroll
      for (int mf = 0; mf < 4; ++mf)
#pragma unroll
        for (int nf = 2; nf < 4; ++nf)
          acc[mf][nf] = __builtin_amdgcn_mfma_f32_16x16x32_bf16(
              af[mf][kk], bfr[nf][kk], acc[mf][nf], 0, 0, 0);
    __builtin_amdgcn_s_setprio(0);
    __builtin_amdgcn_sched_barrier(0);
    __builtin_amdgcn_s_barrier();   // all waves' P1 MFMAs issued => B1 reads done
    __builtin_amdgcn_sched_barrier(0);

    // ---- tail: stage B1(t+2); counted swap wait ----
    if (pf) stageB(g + 2, rb, 32);
    __builtin_amdgcn_sched_barrier(0);
    if (g + 2 < NT)      asm volatile("s_waitcnt vmcnt(6)" ::: "memory");
    else if (g + 1 < NT) asm volatile("s_waitcnt vmcnt(0)" ::: "memory");
    __builtin_amdgcn_s_barrier();
  };

  for (int g2 = 0; g2 < NT; g2 += 2) {
    group(g2, 0);
    group(g2 + 1, 1);
  }
}

// ---------- output projection: out = ctx(bf16) * Wo(bf16)^T, fp32 out --------
// 1D grid 256 with XCD m-band swizzle: XCD i owns m-rows [4i,4i+4) x all n ->
// A fetched once (16MB) + B 8x (64MB); was A 8x (128MB) + B 1x (8MB).
__global__ __launch_bounds__(512, 2) void out_gemm(const bf16_t* __restrict__ ctx,
                                                   const bf16_t* __restrict__ Wo,
                                                   float* __restrict__ out) {
  __shared__ __align__(16) bf16_t As[2][128 * 64];
  __shared__ __align__(16) bf16_t Bs[2][256 * 64];
  const int bid = blockIdx.x;
  const int xi = bid & 7, xj = bid >> 3;
  const int m0 = ((xi << 2) + (xj & 3)) * 128;
  const int n0 = (xj >> 2) * 256;
  f32x4 acc[4][4] = {};
  gemm128x256_loop(ctx, Wo, 2048, m0, n0, As, Bs, acc);
  const int lane = threadIdx.x & 63, wid = threadIdx.x >> 6;
  const int quad = lane >> 4, l16 = lane & 15;
  const int am = (wid >> 2) * 64, bn = (wid & 3) * 64;
#pragma unroll
  for (int mf = 0; mf < 4; ++mf)
#pragma unroll
    for (int nf = 0; nf < 4; ++nf)
#pragma unroll
      for (int r = 0; r < 4; ++r) {
        int gr = m0 + am + mf * 16 + quad * 4 + r;
        int gc = n0 + bn + nf * 16 + l16;
        out[(size_t)gr * 2048 + gc] = acc[mf][nf][r];
      }
}

// ---------- fused mid-stage: RMSNorm+RoPE (q,k) | V transpose | Wo cast ------
// blocks [0,16384): q rows; [16384,20480): k rows; [20480,20992): vtrans;
// [20992,23040): Wo fp32->bf16 cast.
__global__ __launch_bounds__(256) void mid_fused(
    bf16_t* __restrict__ qx, bf16_t* __restrict__ kx,
    const float* __restrict__ qw, const float* __restrict__ kw,
    const float* __restrict__ cs, const float* __restrict__ sn, float qscale,
    const bf16_t* __restrict__ v, bf16_t* __restrict__ vt,
    const float* __restrict__ wo, bf16_t* __restrict__ wob) {
  __shared__ bf16_t t[64][72];
  const int blk = blockIdx.x;
  const int tid = threadIdx.x;
  if (blk < 20480) {
    // ---- RMSNorm + RoPE, one wave per row ----
    bf16_t* basep;
    const float* wgt;
    float outscale;
    int row;
    if (blk < 16384) { basep = qx; wgt = qw; outscale = qscale; row = blk * 4 + (tid >> 6); }
    else { basep = kx; wgt = kw; outscale = 1.0f; row = (blk - 16384) * 4 + (tid >> 6); }
    const int lane = tid & 63;
    const int pos = row & 2047;
    bf16_t* p = basep + (size_t)row * 128;
    float v1 = (float)p[lane];
    float v2 = (float)p[lane + 64];
    float ss = v1 * v1 + v2 * v2;
#pragma unroll
    for (int m = 32; m; m >>= 1) ss += __shfl_xor(ss, m);
    float rr = rsqrtf(ss * (1.0f / 128.0f) + 1e-6f);
    float n1 = v1 * rr * wgt[lane];
    float n2 = v2 * rr * wgt[lane + 64];
    float c1 = cs[pos * 128 + lane],      s1 = sn[pos * 128 + lane];
    float c2 = cs[pos * 128 + lane + 64], s2 = sn[pos * 128 + lane + 64];
    p[lane]      = (bf16_t)((n1 * c1 - n2 * s1) * outscale);
    p[lane + 64] = (bf16_t)((n2 * c2 + n1 * s2) * outscale);
  } else if (blk < 20992) {
    // ---- V transpose: [BG,S,HD] -> [BG,HD,S], 64x64 tile ----
    const int vv = blk - 20480;
    const int t0 = (vv & 31) * 64, d0 = ((vv >> 5) & 1) * 64, bg = vv >> 6;
    const int r = tid >> 3, c = (tid & 7) * 8;
    const bf16_t* src = v + ((size_t)bg * 2048 + t0) * 128 + d0;
#pragma unroll
    for (int it = 0; it < 2; ++it) {
      uint4 val = *(const uint4*)(src + (size_t)(r + it * 32) * 128 + c);
      *(uint4*)&t[r + it * 32][c] = val;
    }
    __syncthreads();
#pragma unroll
    for (int it = 0; it < 2; ++it) {
      int d = r + it * 32;
      bf16_t tmp[8];
#pragma unroll
      for (int j = 0; j < 8; ++j) tmp[j] = t[c + j][d];
      *(uint4*)(vt + ((size_t)bg * 128 + d0 + d) * 2048 + t0 + c) = *(uint4*)tmp;
    }
  } else {
    // ---- Wo fp32 -> bf16 ----
    size_t i = (size_t)(blk - 20992) * 256 + tid;
    const float* g = wo + i * 8;
    f32x4 u0 = *(const f32x4*)g;
    f32x4 u1 = *(const f32x4*)(g + 4);
    bf16x8 vv8;
    vv8[0] = (bf16_t)u0[0]; vv8[1] = (bf16_t)u0[1]; vv8[2] = (bf16_t)u0[2]; vv8[3] = (bf16_t)u0[3];
    vv8[4] = (bf16_t)u1[0]; vv8[5] = (bf16_t)u1[1]; vv8[6] = (bf16_t)u1[2]; vv8[7] = (bf16_t)u1[3];
    *(bf16x8*)(wob + i * 8) = vv8;
  }
}

// ---------- flash attention: GQA head-merged, uniform blocks, transposed QK --
// R18 exact (FROZEN). 1D grid 512: qi=bid>>3, gb=bid&7 -> one (g,b) K/V
// stream per XCD (FETCH 8x lower). Block does q-tiles {qi,127-qi} (33 iters,
// uniform). Per tile: 16 q-rows x 4 heads; K-loop in 64-col tiles.
// S^T = K*Q^T -> packed bf16x4 P-writes + scalar lsum; XOR-swizzled ping-pong
// P LDS, one barrier/iter. Fixed-base softmax (HD^-0.5*log2e in q scale).
__global__ __launch_bounds__(256) void attn_kernel(const bf16_t* __restrict__ q,
    const bf16_t* __restrict__ k, const bf16_t* __restrict__ vt,
    bf16_t* __restrict__ ctx) {
  __shared__ __align__(16) char Plds[2][4][2048];  // [pb][h][16 rows x 128B]
  __shared__ __align__(16) float lred[4][16][4];
  const int bid = blockIdx.x;
  const int qi = bid >> 3, gb = bid & 7;
  const int g = gb & 3, b = gb >> 2;
  const int tid = threadIdx.x, w = tid >> 6, lane = tid & 63;
  const int quad = lane >> 4, l16 = lane & 15;
  const bf16_t* kp = k + ((size_t)b * 4 + g) * 2048 * 128 +
                     (size_t)(w * 16 + l16) * 128 + quad * 8;
  const bf16_t* vp = vt + ((size_t)b * 4 + g) * 128 * 2048 +
                     (size_t)(w * 32 + l16) * 2048 + quad * 8;

#pragma unroll 1
  for (int ph = 0; ph < 2; ++ph) {
    const int qt = ph ? 127 - qi : qi;

    // Q A-fragments: 16 rows (m=l16) per head (64 VGPR)
    bf16x8 qf[4][4];
#pragma unroll
    for (int h = 0; h < 4; ++h)
#pragma unroll
      for (int kk = 0; kk < 4; ++kk)
        qf[h][kk] = *(const bf16x8*)(q +
            (((size_t)b * 16 + g * 4 + h) * 2048 + (size_t)qt * 16 + l16) * 128 +
            kk * 32 + quad * 8);

    f32x4 oacc[4][2] = {};
    float lsum[4] = {};
    const int nkt = (qt >> 2) + 1;
    for (int kt = 0; kt < nkt; ++kt) {
      // K fragments (A-operand of S^T: m = kcol w*16+l16), one fetch, 4 heads
      const bf16_t* kro = kp + (size_t)kt * 64 * 128;
      bf16x8 kf[4];
#pragma unroll
      for (int kk = 0; kk < 4; ++kk) kf[kk] = *(const bf16x8*)(kro + kk * 32);
      // V fragments (B-layout n=l16 -> d = w*32+nd*16+l16), used after barrier
      const bf16_t* vro = vp + (size_t)kt * 64;
      bf16x8 vf[2][2];
#pragma unroll
      for (int nd = 0; nd < 2; ++nd)
#pragma unroll
        for (int kkp = 0; kkp < 2; ++kkp)
          vf[nd][kkp] = *(const bf16x8*)(vro + (size_t)nd * 16 * 2048 + kkp * 32);

      // S^T = K Q^T: C row = kcol_local (quad*4+r), col = qrow_local (l16)
      f32x4 sacc[4] = {};
#pragma unroll
      for (int kk = 0; kk < 4; ++kk)
#pragma unroll
        for (int h = 0; h < 4; ++h)
          sacc[h] = __builtin_amdgcn_mfma_f32_16x16x32_bf16(kf[kk], qf[h][kk],
                                                            sacc[h], 0, 0, 0);
      if (kt == nkt - 1) {  // diagonal tile: mask kcol > qrow
        int kcol = kt * 64 + w * 16 + quad * 4;
        int qrow = qt * 16 + l16;
#pragma unroll
        for (int r = 0; r < 4; ++r)
          if (kcol + r > qrow)
#pragma unroll
            for (int h = 0; h < 4; ++h) sacc[h][r] = -1e30f;
      }

      // softmax numerator + packed 8B P-write (row = qrow l16, 4 consec kcols)
      const int pb = kt & 1;
      const int c0 = w * 2 + (quad >> 1);
      const int woff = l16 * 128 + ((c0 ^ (l16 & 7)) << 4) + ((quad & 1) << 3);
#pragma unroll
      for (int h = 0; h < 4; ++h) {
        float p0 = __builtin_amdgcn_exp2f(sacc[h][0]);
        float p1 = __builtin_amdgcn_exp2f(sacc[h][1]);
        float p2 = __builtin_amdgcn_exp2f(sacc[h][2]);
        float p3 = __builtin_amdgcn_exp2f(sacc[h][3]);
        lsum[h] += (p0 + p1) + (p2 + p3);
        bf16x4 pk;
        pk[0] = (bf16_t)p0; pk[1] = (bf16_t)p1; pk[2] = (bf16_t)p2; pk[3] = (bf16_t)p3;
        *(bf16x4*)(Plds[pb][h] + woff) = pk;
      }
      __syncthreads();  // the only barrier in the loop

      // O += P * V: A = P (m=qrow l16, k=kcol quad*8+j), B = V^T
#pragma unroll
      for (int kkp = 0; kkp < 2; ++kkp) {
        bf16x8 pf[4];
#pragma unroll
        for (int h = 0; h < 4; ++h)
          pf[h] = *(const bf16x8*)(Plds[pb][h] + l16 * 128 +
                                   (((kkp * 4 + quad) ^ (l16 & 7)) << 4));
#pragma unroll
        for (int nd = 0; nd < 2; ++nd)
#pragma unroll
          for (int h = 0; h < 4; ++h)
            oacc[h][nd] = __builtin_amdgcn_mfma_f32_16x16x32_bf16(
                pf[h], vf[nd][kkp], oacc[h][nd], 0, 0, 0);
      }
    }

    // row-sum: lane's lsum covers its 4 kcols at qrow=l16; reduce across quads
    // (lanes l16, l16+16, l16+32, l16+48) then across waves via LDS.
#pragma unroll
    for (int h = 0; h < 4; ++h) {
      float v = lsum[h];
      v += __shfl_xor(v, 16);
      v += __shfl_xor(v, 32);
      if (quad == 0) lred[h][l16][w] = v;
    }
    __syncthreads();
    // epilogue: oacc C-layout row = qrow_local quad*4+r, col = d_local l16
#pragma unroll
    for (int h = 0; h < 4; ++h)
#pragma unroll
      for (int r = 0; r < 4; ++r) {
        int row = quad * 4 + r;
        f32x4 t = *(const f32x4*)lred[h][row];
        float inv = 1.f / (t[0] + t[1] + t[2] + t[3]);
        int pos = qt * 16 + row;
        size_t base = (((size_t)b * 2048 + pos) * 16 + g * 4 + h) * 128;
#pragma unroll
        for (int nd = 0; nd < 2; ++nd)
          ctx[base + w * 32 + nd * 16 + l16] = (bf16_t)(oacc[h][nd][r] * inv);
      }
  }
}

extern "C" void kernel_launch(void* const* d_in, const int* in_sizes, int n_in,
                              void* d_out, int out_size, void* d_ws, size_t ws_size,
                              hipStream_t stream) {
  (void)in_sizes; (void)n_in; (void)out_size; (void)ws_size;
  const float* x    = (const float*)d_in[0];
  const float* cosp = (const float*)d_in[2];
  const float* sinp = (const float*)d_in[3];
  const float* Wq   = (const float*)d_in[4];
  const float* Wk   = (const float*)d_in[5];
  const float* Wv   = (const float*)d_in[6];
  const float* Wo   = (const float*)d_in[7];
  const float* qnw  = (const float*)d_in[8];
  const float* knw  = (const float*)d_in[9];
  float* out = (float*)d_out;

  char* ws = (char*)d_ws;
  bf16_t* qb  = (bf16_t*)(ws);               // 16777216 B
  bf16_t* kb  = (bf16_t*)(ws + 16777216);    //  4194304 B
  bf16_t* vb  = (bf16_t*)(ws + 20971520);    //  4194304 B
  bf16_t* vtb = (bf16_t*)(ws + 25165824);    //  4194304 B
  bf16_t* ctx = (bf16_t*)(ws + 29360128);    // 16777216 B
  bf16_t* xb  = (bf16_t*)(ws + 29360128);    // aliases ctx (dead before attn)
  bf16_t* wqb = (bf16_t*)(ws + 46137344);    //  8388608 B — contiguous with
  bf16_t* wob = (bf16_t*)(ws + 46137344);    //  wkb/wvb => [3072,2048] W
  bf16_t* wkb = (bf16_t*)(ws + 54525952);    //  2097152 B
  bf16_t* wvb = (bf16_t*)(ws + 56623104);    //  2097152 B

  cast_all<<<7168, 256, 0, stream>>>(x, Wq, Wk, Wv, xb, wqb, wkb, wvb);
  qkv_gemm<<<256, 512, 0, stream>>>(xb, wqb, qb, kb, vb);
  // q scale = HD^-0.5 * log2(e) folded for fixed-base exp2 softmax
  mid_fused<<<23040, 256, 0, stream>>>(qb, kb, qnw, knw, cosp, sinp,
                                       0.12751742902f, vb, vtb, Wo, wob);
  attn_kernel<<<512, 256, 0, stream>>>(qb, kb, vtb, ctx);
  out_gemm<<<256, 512, 0, stream>>>(ctx, wob, out);
}